// Round 4
// baseline (1549.573 us; speedup 1.0000x reference)
//
#include <hip/hip_runtime.h>
#include <hip/hip_fp16.h>

// reaction_diffusion, bucketed multi-split + LDS-accumulate gather.
// out[b,v] = tanh(colr[v]*x[b,v] - msgr[v,b] + br[v])
//          +      cold[v]*x[b,v] - msgd[v,b] + bd[v]  + x[b,v]
// r-side runs (dest = ei): payload (other=ej, w_main=wr -> msgr, w_col=wd -> cold)
// d-side runs (dest = ej): payload (other=ei, w_main=wd -> msgd, w_col=wr -> colr)
// Buckets of 128 nodes; per-bucket run capacity 4608 (mean 4096, +8 sigma).

#define BKT_SHIFT 7
#define BKT_NODES 128
#define RCAP 4608
#define CH 4096
#define NB_MAX 512   // padded bucket count for the scan (N <= 65536)

__device__ __forceinline__ unsigned bf16_rne(float f) {
    unsigned u = __float_as_uint(f);
    unsigned rb = (u >> 16) & 1u;
    u += 0x7FFFu + rb;
    return u >> 16;
}

__global__ void zero_kernel(float4* __restrict__ p, int n4) {
    int i = blockIdx.x * blockDim.x + threadIdx.x;
    int s = gridDim.x * blockDim.x;
    float4 z = make_float4(0.f, 0.f, 0.f, 0.f);
    for (; i < n4; i += s) p[i] = z;
}

// x [64, N] -> xt [N, 64] fp32 and xth [N, 64] fp16
__global__ void transpose_kernel(const float* __restrict__ x, float* __restrict__ xt,
                                 __half* __restrict__ xth, int N) {
    __shared__ float tile[64][65];
    int v0 = blockIdx.x * 64;
    int tx = threadIdx.x;   // 0..63
    int ty = threadIdx.y;   // 0..15
    if (v0 + tx < N) {
        for (int b = ty; b < 64; b += 16)
            tile[tx][b] = x[b * N + v0 + tx];
    }
    __syncthreads();
    for (int vl = ty; vl < 64; vl += 16) {
        int v = v0 + vl;
        if (v < N) {
            float val = tile[vl][tx];
            xt[(size_t)v * 64 + tx] = val;
            xth[(size_t)v * 64 + tx] = __float2half(val);
        }
    }
}

// chunked multi-split: count -> scan -> LDS reorder -> 1 atomic/bucket -> coalesced run write
__global__ void __launch_bounds__(256) partition_kernel(
        const int* __restrict__ ei, const int* __restrict__ ej,
        const float* __restrict__ wr, const float* __restrict__ wd,
        int* __restrict__ gcur, int2* __restrict__ runs,
        int E, int NB) {
    __shared__ int cnt[NB_MAX];         // counts, then cursors
    __shared__ int base_a[NB_MAX];      // exclusive chunk-local base
    __shared__ int gb[NB_MAX];          // global base for this chunk's run
    __shared__ int2 buf[CH];            // payloads reordered by bucket
    __shared__ unsigned short posb[CH]; // bucket id per buffered position

    int tid = threadIdx.x;
    int e0 = blockIdx.x * CH;
    int ch_len = min(CH, E - e0);
    if (ch_len <= 0) return;

    for (int side = 0; side < 2; ++side) {
        __syncthreads();
        for (int b = tid; b < NB_MAX; b += 256) cnt[b] = 0;
        __syncthreads();
        // phase 1: count buckets
        for (int t = tid; t < ch_len; t += 256) {
            int de = (side == 0) ? ei[e0 + t] : ej[e0 + t];
            atomicAdd(&cnt[de >> BKT_SHIFT], 1);
        }
        __syncthreads();
        // phase 2: exclusive scan (wave 0)
        if (tid < 64) {
            int carry = 0;
            for (int c = 0; c < NB_MAX / 64; ++c) {
                int idx = c * 64 + tid;
                int val = cnt[idx];
                int scan = val;
                for (int off = 1; off < 64; off <<= 1) {
                    int n = __shfl_up(scan, off, 64);
                    if (tid >= off) scan += n;
                }
                int excl = scan - val + carry;
                base_a[idx] = excl;
                cnt[idx] = excl;            // becomes cursor
                carry += __shfl(scan, 63, 64);
            }
        }
        __syncthreads();
        // phase 3: place payloads into LDS in bucket order
        for (int t = tid; t < ch_len; t += 256) {
            int e = e0 + t;
            int i = ei[e], j = ej[e];
            int de  = (side == 0) ? i : j;
            int oth = (side == 0) ? j : i;
            float wm = (side == 0) ? wr[e] : wd[e];
            float wc = (side == 0) ? wd[e] : wr[e];
            int b = de >> BKT_SHIFT;
            int dl = de & (BKT_NODES - 1);
            int2 pay;
            pay.x = (dl << 17) | oth;                       // 7 + 17 bits
            pay.y = (int)((bf16_rne(wm) << 16) | bf16_rne(wc));
            int p = atomicAdd(&cnt[b], 1);
            buf[p] = pay;
            posb[p] = (unsigned short)b;
        }
        __syncthreads();
        // phase 4: reserve global run space (one atomic per touched bucket)
        for (int b = tid; b < NB; b += 256) {
            int n = cnt[b] - base_a[b];
            gb[b] = (n > 0) ? atomicAdd(&gcur[side * NB + b], n) : 0;
        }
        __syncthreads();
        // phase 5: coalesced copy-out
        for (int t = tid; t < ch_len; t += 256) {
            int b = posb[t];
            int rank = gb[b] + (t - base_a[b]);
            if (rank < RCAP)
                runs[((size_t)(side * NB + b)) * RCAP + rank] = buf[t];
        }
    }
}

// one workgroup per bucket: accumulate both sides into LDS, fused epilogue.
__global__ void __launch_bounds__(512) gather_kernel(
        const float* __restrict__ xt, const __half* __restrict__ xth,
        const int* __restrict__ gcur, const int2* __restrict__ runs,
        const float* __restrict__ br, const float* __restrict__ bd,
        float* __restrict__ outt, int N, int NB) {
    __shared__ float accr[BKT_NODES * 64];   // 32 KB
    __shared__ float accd[BKT_NODES * 64];   // 32 KB
    __shared__ float colr_l[BKT_NODES];
    __shared__ float cold_l[BKT_NODES];

    int tid = threadIdx.x;
    int lane = tid & 63;
    int wid = tid >> 6;            // 0..7
    int b = blockIdx.x;
    int v0 = b << BKT_SHIFT;

    for (int k = tid; k < BKT_NODES * 64; k += 512) { accr[k] = 0.f; accd[k] = 0.f; }
    for (int k = tid; k < BKT_NODES; k += 512) { colr_l[k] = 0.f; cold_l[k] = 0.f; }
    __syncthreads();

    // r-side: msgr += wr * x[ej], cold += wd
    {
        int len = min(gcur[b], RCAP);
        const int2* run = runs + (size_t)b * RCAP;
        for (int k = wid; k < len; k += 8) {
            int2 p = run[k];
            int dl  = (p.x >> 17) & (BKT_NODES - 1);
            int oth = p.x & 0x1FFFF;
            float wm = __uint_as_float(((unsigned)p.y >> 16) << 16);
            float wc = __uint_as_float(((unsigned)p.y & 0xFFFFu) << 16);
            float xo = __half2float(xth[(size_t)oth * 64 + lane]);
            atomicAdd(&accr[dl * 64 + lane], wm * xo);
            if (lane == 0) atomicAdd(&cold_l[dl], wc);
        }
    }
    // d-side: msgd += wd * x[ei], colr += wr
    {
        int len = min(gcur[NB + b], RCAP);
        const int2* run = runs + (size_t)(NB + b) * RCAP;
        for (int k = wid; k < len; k += 8) {
            int2 p = run[k];
            int dl  = (p.x >> 17) & (BKT_NODES - 1);
            int oth = p.x & 0x1FFFF;
            float wm = __uint_as_float(((unsigned)p.y >> 16) << 16);
            float wc = __uint_as_float(((unsigned)p.y & 0xFFFFu) << 16);
            float xo = __half2float(xth[(size_t)oth * 64 + lane]);
            atomicAdd(&accd[dl * 64 + lane], wm * xo);
            if (lane == 0) atomicAdd(&colr_l[dl], wc);
        }
    }
    __syncthreads();
    // epilogue
    for (int vl = wid; vl < BKT_NODES; vl += 8) {
        int v = v0 + vl;
        if (v < N) {
            float xv = xt[(size_t)v * 64 + lane];
            float r = colr_l[vl] * xv - accr[vl * 64 + lane] + br[v];
            float d = cold_l[vl] * xv - accd[vl * 64 + lane] + bd[v];
            outt[(size_t)v * 64 + lane] = tanhf(r) + d + xv;
        }
    }
}

// outt [N, 64] -> out [64, N]
__global__ void transpose_out_kernel(const float* __restrict__ outt,
                                     float* __restrict__ out, int N) {
    __shared__ float tile[64][65];
    int v0 = blockIdx.x * 64;
    int tx = threadIdx.x;   // 0..63
    int ty = threadIdx.y;   // 0..15
    for (int vl = ty; vl < 64; vl += 16) {
        int v = v0 + vl;
        if (v < N)
            tile[vl][tx] = outt[(size_t)v * 64 + tx];
    }
    __syncthreads();
    if (v0 + tx < N) {
        for (int b = ty; b < 64; b += 16)
            out[b * N + v0 + tx] = tile[tx][b];
    }
}

extern "C" void kernel_launch(void* const* d_in, const int* in_sizes, int n_in,
                              void* d_out, int out_size, void* d_ws, size_t ws_size,
                              hipStream_t stream) {
    const float* x  = (const float*)d_in[1];
    const int*   ei = (const int*)d_in[2];
    const int*   ej = (const int*)d_in[3];
    const float* wr = (const float*)d_in[4];
    const float* wd = (const float*)d_in[5];
    const float* br = (const float*)d_in[6];
    const float* bd = (const float*)d_in[7];
    float* out = (float*)d_out;

    int E = in_sizes[2];
    int N = in_sizes[6];
    int NB = (N + BKT_NODES - 1) >> BKT_SHIFT;
    (void)out_size; (void)ws_size; (void)n_in;

    // workspace: xt[N*64 f32] | outt[N*64 f32] | xth[N*64 f16] | gcur[2*NB pad] | runs[2*NB*RCAP int2]
    char* w = (char*)d_ws;
    float* xt   = (float*)w;   w += (size_t)N * 64 * 4;
    float* outt = (float*)w;   w += (size_t)N * 64 * 4;
    __half* xth = (__half*)w;  w += (size_t)N * 64 * 2;
    int* gcur   = (int*)w;     w += (size_t)((2 * NB + 3) / 4) * 4 * 4;
    w = (char*)(((uintptr_t)w + 15) & ~(uintptr_t)15);
    int2* runs  = (int2*)w;

    // zero gcur (padded to multiple of 4 ints)
    zero_kernel<<<4, 256, 0, stream>>>((float4*)gcur, (2 * NB + 3) / 4);

    dim3 tb(64, 16);
    int ntiles = (N + 63) / 64;
    transpose_kernel<<<ntiles, tb, 0, stream>>>(x, xt, xth, N);

    int nchunks = (E + CH - 1) / CH;
    partition_kernel<<<nchunks, 256, 0, stream>>>(ei, ej, wr, wd, gcur, runs, E, NB);

    gather_kernel<<<NB, 512, 0, stream>>>(xt, xth, gcur, runs, br, bd, outt, N, NB);

    transpose_out_kernel<<<ntiles, tb, 0, stream>>>(outt, out, N);
}

// Round 5
// 267.340 us; speedup vs baseline: 5.7963x; 5.7963x over previous
//
#include <hip/hip_runtime.h>
#include <hip/hip_fp16.h>

// reaction_diffusion, 2-stage sort (bucket multisplit -> in-bucket counting sort)
// + per-node-wave register gather.
// out[b,v] = tanh(colr[v]*x[b,v] - msgr[v,b] + br[v])
//          +      cold[v]*x[b,v] - msgd[v,b] + bd[v]  + x[b,v]
// side 0 runs (dest = ei): payload (other=ej, w_main=wr -> msgr, w_col=wd -> cold)
// side 1 runs (dest = ej): payload (other=ei, w_main=wd -> msgd, w_col=wr -> colr)
// payload int2: x = (dl<<17)|other, y = (bf16(w_main)<<16)|bf16(w_col)

#define BKT_SHIFT 7
#define BKT_NODES 128
#define RCAP 4608     // per-bucket run capacity: mean 4096, +8 sigma
#define CH 4096       // partition chunk size
#define NB_MAX 512    // padded bucket count for partition scan (N <= 65536)

__device__ __forceinline__ unsigned bf16_rne(float f) {
    unsigned u = __float_as_uint(f);
    unsigned rb = (u >> 16) & 1u;
    u += 0x7FFFu + rb;
    return u >> 16;
}
__device__ __forceinline__ float bf16_hi(int y) {
    return __uint_as_float((unsigned)y & 0xFFFF0000u);
}
__device__ __forceinline__ float bf16_lo(int y) {
    return __uint_as_float(((unsigned)y) << 16);
}

__global__ void zero_kernel(float4* __restrict__ p, int n4) {
    int i = blockIdx.x * blockDim.x + threadIdx.x;
    int s = gridDim.x * blockDim.x;
    float4 z = make_float4(0.f, 0.f, 0.f, 0.f);
    for (; i < n4; i += s) p[i] = z;
}

// x [64, N] -> xt [N, 64] fp32 and xth [N, 64] fp16
__global__ void transpose_kernel(const float* __restrict__ x, float* __restrict__ xt,
                                 __half* __restrict__ xth, int N) {
    __shared__ float tile[64][65];
    int v0 = blockIdx.x * 64;
    int tx = threadIdx.x;
    int ty = threadIdx.y;
    if (v0 + tx < N) {
        for (int b = ty; b < 64; b += 16)
            tile[tx][b] = x[b * N + v0 + tx];
    }
    __syncthreads();
    for (int vl = ty; vl < 64; vl += 16) {
        int v = v0 + vl;
        if (v < N) {
            float val = tile[vl][tx];
            xt[(size_t)v * 64 + tx] = val;
            xth[(size_t)v * 64 + tx] = __float2half(val);
        }
    }
}

// stage 1: chunked multi-split into buckets of 128 nodes, coalesced run writes.
__global__ void __launch_bounds__(256) partition_kernel(
        const int* __restrict__ ei, const int* __restrict__ ej,
        const float* __restrict__ wr, const float* __restrict__ wd,
        int* __restrict__ gcur, int2* __restrict__ runs,
        int E, int NB) {
    __shared__ int cnt[NB_MAX];
    __shared__ int base_a[NB_MAX];
    __shared__ int gb[NB_MAX];
    __shared__ int2 buf[CH];
    __shared__ unsigned short posb[CH];

    int tid = threadIdx.x;
    int e0 = blockIdx.x * CH;
    int ch_len = min(CH, E - e0);
    if (ch_len <= 0) return;

    for (int side = 0; side < 2; ++side) {
        __syncthreads();
        for (int b = tid; b < NB_MAX; b += 256) cnt[b] = 0;
        __syncthreads();
        for (int t = tid; t < ch_len; t += 256) {
            int de = (side == 0) ? ei[e0 + t] : ej[e0 + t];
            atomicAdd(&cnt[de >> BKT_SHIFT], 1);
        }
        __syncthreads();
        if (tid < 64) {
            int carry = 0;
            for (int c = 0; c < NB_MAX / 64; ++c) {
                int idx = c * 64 + tid;
                int val = cnt[idx];
                int scan = val;
                for (int off = 1; off < 64; off <<= 1) {
                    int n = __shfl_up(scan, off, 64);
                    if (tid >= off) scan += n;
                }
                int excl = scan - val + carry;
                base_a[idx] = excl;
                cnt[idx] = excl;            // becomes cursor
                carry += __shfl(scan, 63, 64);
            }
        }
        __syncthreads();
        for (int t = tid; t < ch_len; t += 256) {
            int e = e0 + t;
            int i = ei[e], j = ej[e];
            int de  = (side == 0) ? i : j;
            int oth = (side == 0) ? j : i;
            float wm = (side == 0) ? wr[e] : wd[e];
            float wc = (side == 0) ? wd[e] : wr[e];
            int b = de >> BKT_SHIFT;
            int dl = de & (BKT_NODES - 1);
            int2 pay;
            pay.x = (dl << 17) | oth;
            pay.y = (int)((bf16_rne(wm) << 16) | bf16_rne(wc));
            int p = atomicAdd(&cnt[b], 1);
            buf[p] = pay;
            posb[p] = (unsigned short)b;
        }
        __syncthreads();
        for (int b = tid; b < NB; b += 256) {
            int n = cnt[b] - base_a[b];
            gb[b] = (n > 0) ? atomicAdd(&gcur[side * NB + b], n) : 0;
        }
        __syncthreads();
        for (int t = tid; t < ch_len; t += 256) {
            int b = posb[t];
            int rank = gb[b] + (t - base_a[b]);
            if (rank < RCAP)
                runs[((size_t)(side * NB + b)) * RCAP + rank] = buf[t];
        }
    }
}

// stage 2: counting-sort each bucket run by destination node (in place),
// emit per-node (base, count) meta.
__global__ void __launch_bounds__(256) csr_kernel(
        const int* __restrict__ gcur, int2* __restrict__ runs,
        int2* __restrict__ meta, int NB, int N) {
    __shared__ int cnt[BKT_NODES];
    __shared__ int cur[BKT_NODES];
    __shared__ int2 src[RCAP];   // 36 KB
    __shared__ int2 dst[RCAP];   // 36 KB

    int sb = blockIdx.x;               // side*NB + b
    int side = (sb < NB) ? 0 : 1;
    int b = sb - side * NB;
    int v0 = b << BKT_SHIFT;
    int len = min(gcur[sb], RCAP);
    size_t roff = (size_t)sb * RCAP;
    int tid = threadIdx.x;

    for (int k = tid; k < BKT_NODES; k += 256) cnt[k] = 0;
    __syncthreads();
    for (int k = tid; k < len; k += 256) {
        int2 p = runs[roff + k];
        src[k] = p;
        atomicAdd(&cnt[(p.x >> 17) & (BKT_NODES - 1)], 1);
    }
    __syncthreads();
    if (tid < 64) {
        int carry = 0;
        for (int c = 0; c < BKT_NODES / 64; ++c) {
            int idx = c * 64 + tid;
            int val = cnt[idx];
            int scan = val;
            for (int off = 1; off < 64; off <<= 1) {
                int n = __shfl_up(scan, off, 64);
                if (tid >= off) scan += n;
            }
            cur[idx] = scan - val + carry;   // exclusive
            carry += __shfl(scan, 63, 64);
        }
    }
    __syncthreads();
    if (tid < BKT_NODES) {
        int v = v0 + tid;
        if (v < N)
            meta[(size_t)side * N + v] = make_int2((int)roff + cur[tid], cnt[tid]);
    }
    __syncthreads();
    for (int k = tid; k < len; k += 256) {
        int2 p = src[k];
        int dl = (p.x >> 17) & (BKT_NODES - 1);
        int pos = atomicAdd(&cur[dl], 1);
        dst[pos] = p;
    }
    __syncthreads();
    for (int k = tid; k < len; k += 256)
        runs[roff + k] = dst[k];
}

// one wave per node, lane=batch: both segments sequential, register acc,
// fused epilogue, coalesced outt write.
__global__ void gather_kernel(const float* __restrict__ xt, const __half* __restrict__ xth,
                              const int2* __restrict__ meta, const int2* __restrict__ runs,
                              const float* __restrict__ br, const float* __restrict__ bd,
                              float* __restrict__ outt, int N) {
    int lane = threadIdx.x & 63;
    int wid = (blockIdx.x * blockDim.x + threadIdx.x) >> 6;
    int nw = (gridDim.x * blockDim.x) >> 6;
    for (int v = wid; v < N; v += nw) {
        int2 mr = meta[v];
        int2 md = meta[(size_t)N + v];

        float accr = 0.f, cold = 0.f;
        {
            const int2* seg = runs + mr.x;
            int n = mr.y;
            int k = 0;
            for (; k + 4 <= n; k += 4) {
                int2 p0 = seg[k], p1 = seg[k + 1], p2 = seg[k + 2], p3 = seg[k + 3];
                float x0 = __half2float(xth[(size_t)(p0.x & 0x1FFFF) * 64 + lane]);
                float x1 = __half2float(xth[(size_t)(p1.x & 0x1FFFF) * 64 + lane]);
                float x2 = __half2float(xth[(size_t)(p2.x & 0x1FFFF) * 64 + lane]);
                float x3 = __half2float(xth[(size_t)(p3.x & 0x1FFFF) * 64 + lane]);
                accr += bf16_hi(p0.y) * x0; cold += bf16_lo(p0.y);
                accr += bf16_hi(p1.y) * x1; cold += bf16_lo(p1.y);
                accr += bf16_hi(p2.y) * x2; cold += bf16_lo(p2.y);
                accr += bf16_hi(p3.y) * x3; cold += bf16_lo(p3.y);
            }
            for (; k < n; ++k) {
                int2 p = seg[k];
                accr += bf16_hi(p.y) * __half2float(xth[(size_t)(p.x & 0x1FFFF) * 64 + lane]);
                cold += bf16_lo(p.y);
            }
        }
        float accd = 0.f, colr = 0.f;
        {
            const int2* seg = runs + md.x;
            int n = md.y;
            int k = 0;
            for (; k + 4 <= n; k += 4) {
                int2 p0 = seg[k], p1 = seg[k + 1], p2 = seg[k + 2], p3 = seg[k + 3];
                float x0 = __half2float(xth[(size_t)(p0.x & 0x1FFFF) * 64 + lane]);
                float x1 = __half2float(xth[(size_t)(p1.x & 0x1FFFF) * 64 + lane]);
                float x2 = __half2float(xth[(size_t)(p2.x & 0x1FFFF) * 64 + lane]);
                float x3 = __half2float(xth[(size_t)(p3.x & 0x1FFFF) * 64 + lane]);
                accd += bf16_hi(p0.y) * x0; colr += bf16_lo(p0.y);
                accd += bf16_hi(p1.y) * x1; colr += bf16_lo(p1.y);
                accd += bf16_hi(p2.y) * x2; colr += bf16_lo(p2.y);
                accd += bf16_hi(p3.y) * x3; colr += bf16_lo(p3.y);
            }
            for (; k < n; ++k) {
                int2 p = seg[k];
                accd += bf16_hi(p.y) * __half2float(xth[(size_t)(p.x & 0x1FFFF) * 64 + lane]);
                colr += bf16_lo(p.y);
            }
        }
        float xv = xt[(size_t)v * 64 + lane];
        float r = colr * xv - accr + br[v];
        float d = cold * xv - accd + bd[v];
        outt[(size_t)v * 64 + lane] = tanhf(r) + d + xv;
    }
}

// outt [N, 64] -> out [64, N]
__global__ void transpose_out_kernel(const float* __restrict__ outt,
                                     float* __restrict__ out, int N) {
    __shared__ float tile[64][65];
    int v0 = blockIdx.x * 64;
    int tx = threadIdx.x;
    int ty = threadIdx.y;
    for (int vl = ty; vl < 64; vl += 16) {
        int v = v0 + vl;
        if (v < N)
            tile[vl][tx] = outt[(size_t)v * 64 + tx];
    }
    __syncthreads();
    if (v0 + tx < N) {
        for (int b = ty; b < 64; b += 16)
            out[b * N + v0 + tx] = tile[tx][b];
    }
}

extern "C" void kernel_launch(void* const* d_in, const int* in_sizes, int n_in,
                              void* d_out, int out_size, void* d_ws, size_t ws_size,
                              hipStream_t stream) {
    const float* x  = (const float*)d_in[1];
    const int*   ei = (const int*)d_in[2];
    const int*   ej = (const int*)d_in[3];
    const float* wr = (const float*)d_in[4];
    const float* wd = (const float*)d_in[5];
    const float* br = (const float*)d_in[6];
    const float* bd = (const float*)d_in[7];
    float* out = (float*)d_out;

    int E = in_sizes[2];
    int N = in_sizes[6];
    int NB = (N + BKT_NODES - 1) >> BKT_SHIFT;
    (void)out_size; (void)ws_size; (void)n_in;

    // workspace: xt[N*64 f32] | outt[N*64 f32] | xth[N*64 f16] | gcur[2*NB pad]
    //          | meta[2*N int2] | runs[2*NB*RCAP int2]
    char* w = (char*)d_ws;
    float* xt   = (float*)w;   w += (size_t)N * 64 * 4;
    float* outt = (float*)w;   w += (size_t)N * 64 * 4;
    __half* xth = (__half*)w;  w += (size_t)N * 64 * 2;
    int* gcur   = (int*)w;     w += (size_t)((2 * NB + 3) / 4) * 4 * 4;
    w = (char*)(((uintptr_t)w + 15) & ~(uintptr_t)15);
    int2* meta  = (int2*)w;    w += (size_t)2 * N * 8;
    int2* runs  = (int2*)w;

    zero_kernel<<<4, 256, 0, stream>>>((float4*)gcur, (2 * NB + 3) / 4);

    dim3 tb(64, 16);
    int ntiles = (N + 63) / 64;
    transpose_kernel<<<ntiles, tb, 0, stream>>>(x, xt, xth, N);

    int nchunks = (E + CH - 1) / CH;
    partition_kernel<<<nchunks, 256, 0, stream>>>(ei, ej, wr, wd, gcur, runs, E, NB);

    csr_kernel<<<2 * NB, 256, 0, stream>>>(gcur, runs, meta, NB, N);

    int gblocks = (N + 3) / 4;   // 4 node-waves per 256-thread block
    gather_kernel<<<gblocks, 256, 0, stream>>>(xt, xth, meta, runs, br, bd, outt, N);

    transpose_out_kernel<<<ntiles, tb, 0, stream>>>(outt, out, N);
}

// Round 6
// 226.007 us; speedup vs baseline: 6.8563x; 1.1829x over previous
//
#include <hip/hip_runtime.h>
#include <hip/hip_fp16.h>

// reaction_diffusion, 2-stage sort (dual-side bucket multisplit -> in-bucket
// counting sort w/ fused col-sums) + scalar-optimized per-node-wave gather.
// out[b,v] = tanh(colr[v]*x[b,v] - msgr[v,b] + br[v])
//          +      cold[v]*x[b,v] - msgd[v,b] + bd[v]  + x[b,v]
// side 0 (dest = ei): payload w_main=wr -> msgr, w_col=wd -> cold
// side 1 (dest = ej): payload w_main=wd -> msgd, w_col=wr -> colr
// payload int2: x = (bkt:9 << 23)|(dl:7 << 16)|(other:16), y = bf16(wm)<<16|bf16(wc)
// NOTE: other packed in 16 bits -> requires N <= 65536 (N = 50000 here).

#define BKT_SHIFT 7
#define BKT_NODES 128
#define RCAP 4608     // per-bucket run capacity: mean 4096, +8 sigma
#define CH 4096       // partition chunk size
#define NBP 512       // padded per-side bin count (N <= 65536)

#define RFL(x) __builtin_amdgcn_readfirstlane(x)

__device__ __forceinline__ unsigned bf16_rne(float f) {
    unsigned u = __float_as_uint(f);
    unsigned rb = (u >> 16) & 1u;
    u += 0x7FFFu + rb;
    return u >> 16;
}
__device__ __forceinline__ float bf16_lo(int y) {
    return __uint_as_float(((unsigned)y) << 16);
}

__global__ void zero_kernel(float4* __restrict__ p, int n4) {
    int i = blockIdx.x * blockDim.x + threadIdx.x;
    int s = gridDim.x * blockDim.x;
    float4 z = make_float4(0.f, 0.f, 0.f, 0.f);
    for (; i < n4; i += s) p[i] = z;
}

// x [64, N] -> xt [N, 64] fp32 and xth [N, 64] fp16
__global__ void transpose_kernel(const float* __restrict__ x, float* __restrict__ xt,
                                 __half* __restrict__ xth, int N) {
    __shared__ float tile[64][65];
    int v0 = blockIdx.x * 64;
    int tx = threadIdx.x;
    int ty = threadIdx.y;
    if (v0 + tx < N) {
        for (int b = ty; b < 64; b += 16)
            tile[tx][b] = x[b * N + v0 + tx];
    }
    __syncthreads();
    for (int vl = ty; vl < 64; vl += 16) {
        int v = v0 + vl;
        if (v < N) {
            float val = tile[vl][tx];
            xt[(size_t)v * 64 + tx] = val;
            xth[(size_t)v * 64 + tx] = __float2half(val);
        }
    }
}

// stage 1: dual-side chunked multi-split, coalesced run writes.
__global__ void __launch_bounds__(512) partition_kernel(
        const int* __restrict__ ei, const int* __restrict__ ej,
        const float* __restrict__ wr, const float* __restrict__ wd,
        int* __restrict__ gcur, int2* __restrict__ runs,
        int E, int NB) {
    __shared__ int cnt[2 * NBP];     // counts -> cursors (concatenated sides)
    __shared__ int base_a[2 * NBP];  // exclusive chunk-local base
    __shared__ int gb[2 * NBP];      // global base for this chunk's run
    __shared__ int2 buf[2 * CH];     // payloads in (side, bucket) order, 64 KB

    int tid = threadIdx.x;
    int e0 = blockIdx.x * CH;
    int ch_len = min(CH, E - e0);
    if (ch_len <= 0) return;

    for (int b = tid; b < 2 * NBP; b += 512) cnt[b] = 0;
    __syncthreads();
    // phase 1: count both sides
    for (int t = tid; t < ch_len; t += 512) {
        int i = ei[e0 + t], j = ej[e0 + t];
        atomicAdd(&cnt[i >> BKT_SHIFT], 1);
        atomicAdd(&cnt[NBP + (j >> BKT_SHIFT)], 1);
    }
    __syncthreads();
    // phase 2: exclusive scan over 1024 concatenated bins (wave 0)
    if (tid < 64) {
        int carry = 0;
        #pragma unroll
        for (int c = 0; c < (2 * NBP) / 64; ++c) {
            int idx = c * 64 + tid;
            int val = cnt[idx];
            int scan = val;
            for (int off = 1; off < 64; off <<= 1) {
                int n = __shfl_up(scan, off, 64);
                if (tid >= off) scan += n;
            }
            int excl = scan - val + carry;
            base_a[idx] = excl;
            cnt[idx] = excl;            // becomes cursor
            carry += __shfl(scan, 63, 64);
        }
    }
    __syncthreads();
    // phase 3: place both payloads per edge into LDS in (side,bucket) order
    for (int t = tid; t < ch_len; t += 512) {
        int e = e0 + t;
        int i = ei[e], j = ej[e];
        float wrv = wr[e], wdv = wd[e];
        unsigned br16 = bf16_rne(wrv), bd16 = bf16_rne(wdv);
        int b0 = i >> BKT_SHIFT;
        int p0 = atomicAdd(&cnt[b0], 1);
        buf[p0] = make_int2((int)(((unsigned)b0 << 23) | ((unsigned)(i & 127) << 16) | (unsigned)j),
                            (int)((br16 << 16) | bd16));
        int b1 = j >> BKT_SHIFT;
        int p1 = atomicAdd(&cnt[NBP + b1], 1);
        buf[p1] = make_int2((int)(((unsigned)b1 << 23) | ((unsigned)(j & 127) << 16) | (unsigned)i),
                            (int)((bd16 << 16) | br16));
    }
    __syncthreads();
    // phase 4: reserve global run space (one atomic per touched side-bucket)
    for (int cb = tid; cb < 2 * NBP; cb += 512) {
        int n = cnt[cb] - base_a[cb];
        if (n > 0) {
            int side = cb >> 9;           // / NBP
            int bkt = cb & (NBP - 1);
            gb[cb] = atomicAdd(&gcur[side * NB + bkt], n);
        }
    }
    __syncthreads();
    // phase 5: coalesced copy-out (side0 region is exactly [0, ch_len))
    int total = 2 * ch_len;
    for (int t = tid; t < total; t += 512) {
        int2 p = buf[t];
        int side = (t >= ch_len) ? 1 : 0;
        int bkt = ((unsigned)p.x >> 23) & 0x1FF;
        int cb = side * NBP + bkt;
        int rank = gb[cb] + (t - base_a[cb]);
        if (rank < RCAP)
            runs[((size_t)(side * NB + bkt)) * RCAP + rank] = p;
    }
}

// stage 2: counting-sort each bucket run by dest node (in place), emit
// per-node meta (base, count, col_sum) as int4.
__global__ void __launch_bounds__(512) csr_kernel(
        const int* __restrict__ gcur, int2* __restrict__ runs,
        int4* __restrict__ meta, int NB, int N) {
    __shared__ int cnt[BKT_NODES];
    __shared__ int cur[BKT_NODES];
    __shared__ float csum[BKT_NODES];
    __shared__ int2 src[RCAP];   // 36 KB
    __shared__ int2 dst[RCAP];   // 36 KB

    int sb = blockIdx.x;               // side*NB + b
    int side = (sb >= NB) ? 1 : 0;
    int b = sb - side * NB;
    int v0 = b << BKT_SHIFT;
    int len = min(gcur[sb], RCAP);
    size_t roff = (size_t)sb * RCAP;
    int tid = threadIdx.x;

    if (tid < BKT_NODES) { cnt[tid] = 0; csum[tid] = 0.f; }
    __syncthreads();
    for (int k = tid; k < len; k += 512) {
        int2 p = runs[roff + k];
        src[k] = p;
        int dl = ((unsigned)p.x >> 16) & 0x7F;
        atomicAdd(&cnt[dl], 1);
        atomicAdd(&csum[dl], bf16_lo(p.y));
    }
    __syncthreads();
    if (tid < 64) {
        int carry = 0;
        #pragma unroll
        for (int c = 0; c < BKT_NODES / 64; ++c) {
            int idx = c * 64 + tid;
            int val = cnt[idx];
            int scan = val;
            for (int off = 1; off < 64; off <<= 1) {
                int n = __shfl_up(scan, off, 64);
                if (tid >= off) scan += n;
            }
            cur[idx] = scan - val + carry;   // exclusive
            carry += __shfl(scan, 63, 64);
        }
    }
    __syncthreads();
    if (tid < BKT_NODES) {
        int v = v0 + tid;
        if (v < N)
            meta[(size_t)side * N + v] =
                make_int4((int)roff + cur[tid], cnt[tid], __float_as_int(csum[tid]), 0);
    }
    __syncthreads();
    for (int k = tid; k < len; k += 512) {
        int2 p = src[k];
        int dl = ((unsigned)p.x >> 16) & 0x7F;
        int pos = atomicAdd(&cur[dl], 1);
        dst[pos] = p;
    }
    __syncthreads();
    for (int k = tid; k < len; k += 512)
        runs[roff + k] = dst[k];
}

// scalar-uniform segment accumulate: payloads/weights forced to SGPRs,
// per-lane work is just the fp16 gather + fmac.
__device__ __forceinline__ float seg_accum(const int2* __restrict__ seg, int n,
                                           const __half* __restrict__ xth, int lane) {
    float acc = 0.f;
    int k = 0;
    for (; k + 8 <= n; k += 8) {
        int2 p0 = seg[k + 0], p1 = seg[k + 1], p2 = seg[k + 2], p3 = seg[k + 3];
        int2 p4 = seg[k + 4], p5 = seg[k + 5], p6 = seg[k + 6], p7 = seg[k + 7];
        int o0 = RFL(p0.x) & 0xFFFF; int o1 = RFL(p1.x) & 0xFFFF;
        int o2 = RFL(p2.x) & 0xFFFF; int o3 = RFL(p3.x) & 0xFFFF;
        int o4 = RFL(p4.x) & 0xFFFF; int o5 = RFL(p5.x) & 0xFFFF;
        int o6 = RFL(p6.x) & 0xFFFF; int o7 = RFL(p7.x) & 0xFFFF;
        float x0 = __half2float(xth[((size_t)o0 << 6) + lane]);
        float x1 = __half2float(xth[((size_t)o1 << 6) + lane]);
        float x2 = __half2float(xth[((size_t)o2 << 6) + lane]);
        float x3 = __half2float(xth[((size_t)o3 << 6) + lane]);
        float x4 = __half2float(xth[((size_t)o4 << 6) + lane]);
        float x5 = __half2float(xth[((size_t)o5 << 6) + lane]);
        float x6 = __half2float(xth[((size_t)o6 << 6) + lane]);
        float x7 = __half2float(xth[((size_t)o7 << 6) + lane]);
        float w0 = __uint_as_float((unsigned)RFL(p0.y) & 0xFFFF0000u);
        float w1 = __uint_as_float((unsigned)RFL(p1.y) & 0xFFFF0000u);
        float w2 = __uint_as_float((unsigned)RFL(p2.y) & 0xFFFF0000u);
        float w3 = __uint_as_float((unsigned)RFL(p3.y) & 0xFFFF0000u);
        float w4 = __uint_as_float((unsigned)RFL(p4.y) & 0xFFFF0000u);
        float w5 = __uint_as_float((unsigned)RFL(p5.y) & 0xFFFF0000u);
        float w6 = __uint_as_float((unsigned)RFL(p6.y) & 0xFFFF0000u);
        float w7 = __uint_as_float((unsigned)RFL(p7.y) & 0xFFFF0000u);
        acc = fmaf(w0, x0, acc); acc = fmaf(w1, x1, acc);
        acc = fmaf(w2, x2, acc); acc = fmaf(w3, x3, acc);
        acc = fmaf(w4, x4, acc); acc = fmaf(w5, x5, acc);
        acc = fmaf(w6, x6, acc); acc = fmaf(w7, x7, acc);
    }
    for (; k < n; ++k) {
        int2 p = seg[k];
        int o = RFL(p.x) & 0xFFFF;
        float w = __uint_as_float((unsigned)RFL(p.y) & 0xFFFF0000u);
        acc = fmaf(w, __half2float(xth[((size_t)o << 6) + lane]), acc);
    }
    return acc;
}

// one wave per node, lane=batch; fused epilogue, coalesced outt write.
__global__ void __launch_bounds__(256) gather_kernel(
        const float* __restrict__ xt, const __half* __restrict__ xth,
        const int4* __restrict__ meta, const int2* __restrict__ runs,
        const float* __restrict__ br, const float* __restrict__ bd,
        float* __restrict__ outt, int N) {
    int lane = threadIdx.x & 63;
    int v = RFL(blockIdx.x * 4 + (threadIdx.x >> 6));
    if (v >= N) return;
    int4 mr = meta[v];
    int4 md = meta[(size_t)N + v];
    int rbase = RFL(mr.x), rn = RFL(mr.y);
    int dbase = RFL(md.x), dn = RFL(md.y);
    float cold = __int_as_float(RFL(mr.z));
    float colr = __int_as_float(RFL(md.z));

    float accr = seg_accum(runs + rbase, rn, xth, lane);
    float accd = seg_accum(runs + dbase, dn, xth, lane);

    float xv = xt[((size_t)v << 6) + lane];
    float r = colr * xv - accr + br[v];
    float d = cold * xv - accd + bd[v];
    outt[((size_t)v << 6) + lane] = tanhf(r) + d + xv;
}

// outt [N, 64] -> out [64, N]
__global__ void transpose_out_kernel(const float* __restrict__ outt,
                                     float* __restrict__ out, int N) {
    __shared__ float tile[64][65];
    int v0 = blockIdx.x * 64;
    int tx = threadIdx.x;
    int ty = threadIdx.y;
    for (int vl = ty; vl < 64; vl += 16) {
        int v = v0 + vl;
        if (v < N)
            tile[vl][tx] = outt[(size_t)v * 64 + tx];
    }
    __syncthreads();
    if (v0 + tx < N) {
        for (int b = ty; b < 64; b += 16)
            out[b * N + v0 + tx] = tile[tx][b];
    }
}

extern "C" void kernel_launch(void* const* d_in, const int* in_sizes, int n_in,
                              void* d_out, int out_size, void* d_ws, size_t ws_size,
                              hipStream_t stream) {
    const float* x  = (const float*)d_in[1];
    const int*   ei = (const int*)d_in[2];
    const int*   ej = (const int*)d_in[3];
    const float* wr = (const float*)d_in[4];
    const float* wd = (const float*)d_in[5];
    const float* br = (const float*)d_in[6];
    const float* bd = (const float*)d_in[7];
    float* out = (float*)d_out;

    int E = in_sizes[2];
    int N = in_sizes[6];
    int NB = (N + BKT_NODES - 1) >> BKT_SHIFT;
    (void)out_size; (void)ws_size; (void)n_in;

    // workspace: xt[N*64 f32] | outt[N*64 f32] | xth[N*64 f16] | gcur[2*NB pad]
    //          | meta[2*N int4] | runs[2*NB*RCAP int2]   (~62 MB total)
    char* w = (char*)d_ws;
    float* xt   = (float*)w;   w += (size_t)N * 64 * 4;
    float* outt = (float*)w;   w += (size_t)N * 64 * 4;
    __half* xth = (__half*)w;  w += (size_t)N * 64 * 2;
    int* gcur   = (int*)w;     w += (size_t)((2 * NB + 3) / 4) * 4 * 4;
    w = (char*)(((uintptr_t)w + 15) & ~(uintptr_t)15);
    int4* meta  = (int4*)w;    w += (size_t)2 * N * 16;
    int2* runs  = (int2*)w;

    zero_kernel<<<4, 256, 0, stream>>>((float4*)gcur, (2 * NB + 3) / 4);

    dim3 tb(64, 16);
    int ntiles = (N + 63) / 64;
    transpose_kernel<<<ntiles, tb, 0, stream>>>(x, xt, xth, N);

    int nchunks = (E + CH - 1) / CH;
    partition_kernel<<<nchunks, 512, 0, stream>>>(ei, ej, wr, wd, gcur, runs, E, NB);

    csr_kernel<<<2 * NB, 512, 0, stream>>>(gcur, runs, meta, NB, N);

    int gblocks = (N + 3) / 4;   // 4 node-waves per 256-thread block
    gather_kernel<<<gblocks, 256, 0, stream>>>(xt, xth, meta, runs, br, bd, outt, N);

    transpose_out_kernel<<<ntiles, tb, 0, stream>>>(outt, out, N);
}

// Round 7
// 224.277 us; speedup vs baseline: 6.9092x; 1.0077x over previous
//
#include <hip/hip_runtime.h>
#include <hip/hip_fp16.h>

// reaction_diffusion, 2-stage sort (dual-side bucket multisplit -> in-bucket
// counting sort w/ fused col-sums, compact quad-aligned payloads) +
// paired-half2 per-node-wave gather.
// out[b,v] = tanh(colr[v]*x[b,v] - msgr[v,b] + br[v])
//          +      cold[v]*x[b,v] - msgd[v,b] + bd[v]  + x[b,v]
// side 0 (dest = ei): w_main=wr -> msgr, w_col=wd -> cold
// side 1 (dest = ej): w_main=wd -> msgd, w_col=wr -> colr
// stage-1 payload int2: x = (bkt:9<<23)|(dl:7<<16)|(other:16), y = bf16(wm)<<16|bf16(wc)
// stage-2 compact payload int: (bf16(wm)<<16)|other:16  -- requires N <= 65536

#define BKT_SHIFT 7
#define BKT_NODES 128
#define RCAP 4608     // per-bucket run capacity: mean 4096, +8 sigma
#define RCAP2 4992    // 4608 + 128*3 max quad padding (exact worst case)
#define CH 4096       // partition chunk size
#define NBP 512       // padded per-side bin count (N <= 65536)

#define RFL(x) __builtin_amdgcn_readfirstlane(x)

__device__ __forceinline__ unsigned bf16_rne(float f) {
    unsigned u = __float_as_uint(f);
    unsigned rb = (u >> 16) & 1u;
    u += 0x7FFFu + rb;
    return u >> 16;
}
__device__ __forceinline__ float bf16_lo(int y) {
    return __uint_as_float(((unsigned)y) << 16);
}

__global__ void zero_kernel(float4* __restrict__ p, int n4) {
    int i = blockIdx.x * blockDim.x + threadIdx.x;
    int s = gridDim.x * blockDim.x;
    float4 z = make_float4(0.f, 0.f, 0.f, 0.f);
    for (; i < n4; i += s) p[i] = z;
}

// x [64, N] -> xth [N, 64] fp16
__global__ void transpose_kernel(const float* __restrict__ x, __half* __restrict__ xth, int N) {
    __shared__ float tile[64][65];
    int v0 = blockIdx.x * 64;
    int tx = threadIdx.x;
    int ty = threadIdx.y;
    if (v0 + tx < N) {
        for (int b = ty; b < 64; b += 16)
            tile[tx][b] = x[b * N + v0 + tx];
    }
    __syncthreads();
    for (int vl = ty; vl < 64; vl += 16) {
        int v = v0 + vl;
        if (v < N)
            xth[(size_t)v * 64 + tx] = __float2half(tile[vl][tx]);
    }
}

// stage 1: dual-side chunked multi-split, coalesced run writes.
__global__ void __launch_bounds__(512) partition_kernel(
        const int* __restrict__ ei, const int* __restrict__ ej,
        const float* __restrict__ wr, const float* __restrict__ wd,
        int* __restrict__ gcur, int2* __restrict__ runs,
        int E, int NB) {
    __shared__ int cnt[2 * NBP];
    __shared__ int base_a[2 * NBP];
    __shared__ int gb[2 * NBP];
    __shared__ int2 buf[2 * CH];     // 64 KB

    int tid = threadIdx.x;
    int e0 = blockIdx.x * CH;
    int ch_len = min(CH, E - e0);
    if (ch_len <= 0) return;

    for (int b = tid; b < 2 * NBP; b += 512) cnt[b] = 0;
    __syncthreads();
    for (int t = tid; t < ch_len; t += 512) {
        int i = ei[e0 + t], j = ej[e0 + t];
        atomicAdd(&cnt[i >> BKT_SHIFT], 1);
        atomicAdd(&cnt[NBP + (j >> BKT_SHIFT)], 1);
    }
    __syncthreads();
    if (tid < 64) {
        int carry = 0;
        #pragma unroll
        for (int c = 0; c < (2 * NBP) / 64; ++c) {
            int idx = c * 64 + tid;
            int val = cnt[idx];
            int scan = val;
            for (int off = 1; off < 64; off <<= 1) {
                int n = __shfl_up(scan, off, 64);
                if (tid >= off) scan += n;
            }
            int excl = scan - val + carry;
            base_a[idx] = excl;
            cnt[idx] = excl;            // becomes cursor
            carry += __shfl(scan, 63, 64);
        }
    }
    __syncthreads();
    for (int t = tid; t < ch_len; t += 512) {
        int e = e0 + t;
        int i = ei[e], j = ej[e];
        float wrv = wr[e], wdv = wd[e];
        unsigned br16 = bf16_rne(wrv), bd16 = bf16_rne(wdv);
        int b0 = i >> BKT_SHIFT;
        int p0 = atomicAdd(&cnt[b0], 1);
        buf[p0] = make_int2((int)(((unsigned)b0 << 23) | ((unsigned)(i & 127) << 16) | (unsigned)j),
                            (int)((br16 << 16) | bd16));
        int b1 = j >> BKT_SHIFT;
        int p1 = atomicAdd(&cnt[NBP + b1], 1);
        buf[p1] = make_int2((int)(((unsigned)b1 << 23) | ((unsigned)(j & 127) << 16) | (unsigned)i),
                            (int)((bd16 << 16) | br16));
    }
    __syncthreads();
    for (int cb = tid; cb < 2 * NBP; cb += 512) {
        int n = cnt[cb] - base_a[cb];
        if (n > 0) {
            int side = cb >> 9;
            int bkt = cb & (NBP - 1);
            gb[cb] = atomicAdd(&gcur[side * NB + bkt], n);
        }
    }
    __syncthreads();
    int total = 2 * ch_len;
    for (int t = tid; t < total; t += 512) {
        int2 p = buf[t];
        int side = (t >= ch_len) ? 1 : 0;
        int bkt = ((unsigned)p.x >> 23) & 0x1FF;
        int cb = side * NBP + bkt;
        int rank = gb[cb] + (t - base_a[cb]);
        if (rank < RCAP)
            runs[((size_t)(side * NB + bkt)) * RCAP + rank] = p;
    }
}

// stage 2: counting-sort each bucket run by dest node into compact 4-byte
// payloads with quad-aligned, zero-padded segments; emit per-node meta
// (base, count, col_sum).
__global__ void __launch_bounds__(512) csr_kernel(
        const int* __restrict__ gcur, const int2* __restrict__ runs,
        int* __restrict__ runs2, int4* __restrict__ meta, int NB, int N) {
    __shared__ int cnt[BKT_NODES];
    __shared__ int cur[BKT_NODES];
    __shared__ int pb[BKT_NODES];
    __shared__ float csum[BKT_NODES];
    __shared__ int src_c[RCAP];                 // 18 KB
    __shared__ unsigned char dlb[RCAP];         // 4.5 KB
    __shared__ int dst[RCAP2];                  // 19.5 KB
    __shared__ int total_s;

    int sb = blockIdx.x;               // side*NB + b
    int side = (sb >= NB) ? 1 : 0;
    int b = sb - side * NB;
    int v0 = b << BKT_SHIFT;
    int len = min(gcur[sb], RCAP);
    size_t roff = (size_t)sb * RCAP;
    size_t roff2 = (size_t)sb * RCAP2;
    int tid = threadIdx.x;

    if (tid < BKT_NODES) { cnt[tid] = 0; csum[tid] = 0.f; }
    __syncthreads();
    for (int k = tid; k < len; k += 512) {
        int2 p = runs[roff + k];
        int dl = ((unsigned)p.x >> 16) & 0x7F;
        src_c[k] = (int)(((unsigned)p.y & 0xFFFF0000u) | ((unsigned)p.x & 0xFFFFu));
        dlb[k] = (unsigned char)dl;
        atomicAdd(&cnt[dl], 1);
        atomicAdd(&csum[dl], bf16_lo(p.y));
    }
    __syncthreads();
    if (tid < 64) {
        int carry = 0;
        #pragma unroll
        for (int c = 0; c < BKT_NODES / 64; ++c) {
            int idx = c * 64 + tid;
            int val = (cnt[idx] + 3) & ~3;       // quad-padded
            int scan = val;
            for (int off = 1; off < 64; off <<= 1) {
                int n = __shfl_up(scan, off, 64);
                if (tid >= off) scan += n;
            }
            int excl = scan - val + carry;
            pb[idx] = excl;
            cur[idx] = excl;
            carry += __shfl(scan, 63, 64);
        }
        if (tid == 63) total_s = carry;
    }
    __syncthreads();
    if (tid < BKT_NODES) {
        int v = v0 + tid;
        if (v < N)
            meta[(size_t)side * N + v] =
                make_int4((int)(roff2 + pb[tid]), cnt[tid], __float_as_int(csum[tid]), 0);
        int pc = (cnt[tid] + 3) & ~3;
        for (int t = cnt[tid]; t < pc; ++t) dst[pb[tid] + t] = 0;   // zero pads
    }
    __syncthreads();
    for (int k = tid; k < len; k += 512) {
        int dl = dlb[k];
        int pos = atomicAdd(&cur[dl], 1);
        dst[pos] = src_c[k];
    }
    __syncthreads();
    int total = total_s;
    for (int k = tid; k < total; k += 512)
        runs2[roff2 + k] = dst[k];
}

// process one payload pair: lanes 0-31 -> edge A, lanes 32-63 -> edge B,
// each lane covers 2 batches via half2.
__device__ __forceinline__ void pair_acc(int pA, int pB,
                                         const __half2* __restrict__ xth2,
                                         int halfl, bool hi, float2& acc) {
    int oA = RFL(pA) & 0xFFFF;
    int oB = RFL(pB) & 0xFFFF;
    float wA = __uint_as_float((unsigned)RFL(pA) & 0xFFFF0000u);
    float wB = __uint_as_float((unsigned)RFL(pB) & 0xFFFF0000u);
    int o = hi ? oB : oA;
    float w = hi ? wB : wA;
    float2 xf = __half22float2(xth2[((size_t)o << 5) + halfl]);
    acc.x = fmaf(w, xf.x, acc.x);
    acc.y = fmaf(w, xf.y, acc.y);
}

// one wave per node: both sides interleaved for MLP, cross-half shfl reduce,
// fused epilogue, float2 coalesced outt write from lanes 0-31.
__global__ void __launch_bounds__(256) gather_kernel(
        const __half2* __restrict__ xth2, const int* __restrict__ runs2,
        const int4* __restrict__ meta,
        const float* __restrict__ br, const float* __restrict__ bd,
        float2* __restrict__ outt2, int N) {
    int lane = threadIdx.x & 63;
    int halfl = lane & 31;
    bool hi = lane >= 32;
    int v = blockIdx.x * 4 + (threadIdx.x >> 6);
    if (v >= N) return;
    int4 mr = meta[v];
    int4 md = meta[(size_t)N + v];
    int rbase = RFL(mr.x), rn = RFL(mr.y);
    int dbase = RFL(md.x), dn = RFL(md.y);
    float cold = __int_as_float(RFL(mr.z));
    float colr = __int_as_float(RFL(md.z));

    const int4* sr = (const int4*)(runs2 + rbase);   // 16B-aligned by construction
    const int4* sd = (const int4*)(runs2 + dbase);
    int nqr = (rn + 3) >> 2;
    int nqd = (dn + 3) >> 2;
    int nq = max(nqr, nqd);
    float2 accr = make_float2(0.f, 0.f);
    float2 accd = make_float2(0.f, 0.f);
    for (int q = 0; q < nq; ++q) {
        if (q < nqr) {
            int4 qa = sr[q];
            pair_acc(qa.x, qa.y, xth2, halfl, hi, accr);
            pair_acc(qa.z, qa.w, xth2, halfl, hi, accr);
        }
        if (q < nqd) {
            int4 qb = sd[q];
            pair_acc(qb.x, qb.y, xth2, halfl, hi, accd);
            pair_acc(qb.z, qb.w, xth2, halfl, hi, accd);
        }
    }
    // combine even-edge (lanes 0-31) and odd-edge (lanes 32-63) partial sums
    accr.x += __shfl_xor(accr.x, 32);
    accr.y += __shfl_xor(accr.y, 32);
    accd.x += __shfl_xor(accd.x, 32);
    accd.y += __shfl_xor(accd.y, 32);

    float brv = br[v], bdv = bd[v];
    float2 xv = __half22float2(xth2[((size_t)v << 5) + halfl]);
    float r0 = colr * xv.x - accr.x + brv;
    float r1 = colr * xv.y - accr.y + brv;
    float d0 = cold * xv.x - accd.x + bdv;
    float d1 = cold * xv.y - accd.y + bdv;
    float2 res;
    res.x = tanhf(r0) + d0 + xv.x;
    res.y = tanhf(r1) + d1 + xv.y;
    if (!hi)
        outt2[((size_t)v << 5) + halfl] = res;
}

// outt [N, 64] -> out [64, N]
__global__ void transpose_out_kernel(const float* __restrict__ outt,
                                     float* __restrict__ out, int N) {
    __shared__ float tile[64][65];
    int v0 = blockIdx.x * 64;
    int tx = threadIdx.x;
    int ty = threadIdx.y;
    for (int vl = ty; vl < 64; vl += 16) {
        int v = v0 + vl;
        if (v < N)
            tile[vl][tx] = outt[(size_t)v * 64 + tx];
    }
    __syncthreads();
    if (v0 + tx < N) {
        for (int b = ty; b < 64; b += 16)
            out[b * N + v0 + tx] = tile[tx][b];
    }
}

extern "C" void kernel_launch(void* const* d_in, const int* in_sizes, int n_in,
                              void* d_out, int out_size, void* d_ws, size_t ws_size,
                              hipStream_t stream) {
    const float* x  = (const float*)d_in[1];
    const int*   ei = (const int*)d_in[2];
    const int*   ej = (const int*)d_in[3];
    const float* wr = (const float*)d_in[4];
    const float* wd = (const float*)d_in[5];
    const float* br = (const float*)d_in[6];
    const float* bd = (const float*)d_in[7];
    float* out = (float*)d_out;

    int E = in_sizes[2];
    int N = in_sizes[6];
    int NB = (N + BKT_NODES - 1) >> BKT_SHIFT;
    (void)out_size; (void)ws_size; (void)n_in;

    // workspace: outt[N*64 f32] | xth[N*64 f16] | gcur[2*NB pad] | meta[2*N int4]
    //          | runs[2*NB*RCAP int2] | runs2[2*NB*RCAP2 int]   (~65 MB)
    char* w = (char*)d_ws;
    float* outt = (float*)w;   w += (size_t)N * 64 * 4;
    __half* xth = (__half*)w;  w += (size_t)N * 64 * 2;
    int* gcur   = (int*)w;     w += (size_t)((2 * NB + 3) / 4) * 4 * 4;
    w = (char*)(((uintptr_t)w + 15) & ~(uintptr_t)15);
    int4* meta  = (int4*)w;    w += (size_t)2 * N * 16;
    int2* runs  = (int2*)w;    w += (size_t)2 * NB * RCAP * 8;
    int* runs2  = (int*)w;

    zero_kernel<<<4, 256, 0, stream>>>((float4*)gcur, (2 * NB + 3) / 4);

    dim3 tb(64, 16);
    int ntiles = (N + 63) / 64;
    transpose_kernel<<<ntiles, tb, 0, stream>>>(x, xth, N);

    int nchunks = (E + CH - 1) / CH;
    partition_kernel<<<nchunks, 512, 0, stream>>>(ei, ej, wr, wd, gcur, runs, E, NB);

    csr_kernel<<<2 * NB, 512, 0, stream>>>(gcur, runs, runs2, meta, NB, N);

    int gblocks = (N + 3) / 4;   // 4 node-waves per 256-thread block
    gather_kernel<<<gblocks, 256, 0, stream>>>((const __half2*)xth, runs2, meta,
                                               br, bd, (float2*)outt, N);

    transpose_out_kernel<<<ntiles, tb, 0, stream>>>(outt, out, N);
}